// Round 18
// baseline (65.519 us; speedup 1.0000x reference)
//
#include <hip/hip_runtime.h>

// SE(2) depthwise group conv via bf16 MFMA 32x32x16 (fp32 accum), Delta4-packed,
// LDS-transpose wave-private epilogue + NT 256B stores.
//
// out[b,c,t,y,x] = sum_{o,dy,dx} W[c,t,o,dy,dx] * x[b,c,o,y+dy-2,x+dx-2]
// GEMM per (b,c): D[m=32 x-pix][n=(t + 8*Dlt)], Dlt in {0..3} packs FOUR
// output rows per MFMA set. K = 8 dyr x 5 dx x 8 o = 320 = 20 steps of 16.
// B[(dyr,dx,o)][(t,Dlt)] = w[t][dyr-Dlt, dx] (0 if dyr-Dlt outside 0..4).
// Exact: dyr = dy + Dlt reindexes the row sum; all 32 N-cols useful.
// mfma_f32_32x32x16_bf16: A lane l: row m=l&31 (x-pix), k=8*(l>>5)+j ->
//   tap tr=2s+hi (hi=l>>5), o=j.  B lane: col=l&31, same k.
//   D lane l: col=l&31=(t+8*Dlt), row=(reg&3)+8*(reg>>2)+4*hi = x-pix.
// Block = 16 rows x 64 cols of one (b,c); 4 waves; wave wv: y_base=wv*4,
// 2 super-iters (x0=0,32) x 20 MFMA = 40 MFMA/wave (was 64 16x16 MFMAs).
// LDS union 34944 B: stage [20][68][8] bf16 = 21760 B; epil f32
// [8 t][16 y pitch 68]. Grid 4096, XCD-chunked swizzle. NT row stores.
// Weights: wtab3[c][n32][tr40][o8] bf16 = 640 KB in d_ws (L2-resident).

typedef short bf16x8 __attribute__((ext_vector_type(8)));
typedef float f32x4 __attribute__((ext_vector_type(4)));
typedef float f32x16 __attribute__((ext_vector_type(16)));

#define EPIL_TS 1092   // floats per t-plane (16*68 + 4)
#define EPIL_RP 68     // row pitch in floats

__device__ inline unsigned short f2bf(float f) {   // RNE f32->bf16
    unsigned int u = __float_as_uint(f);
    u += 0x7fffu + ((u >> 16) & 1u);
    return (unsigned short)(u >> 16);
}
__device__ inline unsigned pk2(float a, float b) {
    return (unsigned)f2bf(a) | ((unsigned)f2bf(b) << 16);
}

// cos/sin of 2*pi*t/8, f32. NN-rounding margins >=0.035 -> table-vs-libm safe.
__device__ __constant__ float CA8[8] = {1.0f, 0.70710678f, 0.0f, -0.70710678f,
                                        -1.0f, -0.70710678f, 0.0f, 0.70710678f};
__device__ __constant__ float SA8[8] = {0.0f, 0.70710678f, 1.0f, 0.70710678f,
                                        0.0f, -0.70710678f, -1.0f, -0.70710678f};

__device__ inline float rot_w(const float* __restrict__ kern, int c, int t,
                              int o, int dy, int dx) {
    float ca = CA8[t], sa = SA8[t];
    float xx = (float)dx - 2.0f, yy = (float)dy - 2.0f;
    int iy = (int)rintf(sa * xx + ca * yy + 2.0f);  // RNE == jnp.round
    int ix = (int)rintf(ca * xx - sa * yy + 2.0f);
    if (iy >= 0 && iy < 5 && ix >= 0 && ix < 5) {
        int tp = (o - t) & 7;
        return kern[(c * 8 + tp) * 25 + iy * 5 + ix];
    }
    return 0.0f;
}

// wtab3[((c*32 + n)*40 + tr)*8 + o]; n = t + 8*Dlt; 327680 bf16 = 640 KB
__global__ __launch_bounds__(256)
void build_w3(const float* __restrict__ kern, unsigned short* __restrict__ wtab) {
    int e = blockIdx.x * 256 + threadIdx.x;
    if (e >= 327680) return;
    int o  = e & 7;
    int tr = (e >> 3) % 40;
    int n  = (e / 320) & 31;
    int c  = e / 10240;
    int t  = n & 7, dlt = n >> 3;
    int dyr = tr / 5, dx = tr - 5 * dyr;
    int dy  = dyr - dlt;
    float w = (dy >= 0 && dy < 5) ? rot_w(kern, c, t, o, dy, dx) : 0.0f;
    wtab[e] = f2bf(w);
}

template <bool TAB>
__global__ __launch_bounds__(256)
void se2_mfma(const float* __restrict__ x, const float* __restrict__ kern,
              const unsigned short* __restrict__ wtab, float* __restrict__ out) {
    // union: stage (21760 B, shorts) / epil (34944 B, f32) / fallback ldsw
    __shared__ __align__(16) float ldsbuf[8 * EPIL_TS];   // 34944 B
    unsigned short* stage = reinterpret_cast<unsigned short*>(ldsbuf);
    float* epil = ldsbuf;

    // XCD-chunked bijective swizzle: 4096 blocks, 8 XCDs, 512 per XCD.
    const int bid = (blockIdx.x & 7) * 512 + (blockIdx.x >> 3);
    const int xh2 = bid & 1;           // x half: cols 0-63 / 64-127
    const int ys  = (bid >> 1) & 7;    // 8 row-strips of 16
    const int bc  = bid >> 4;          // b*32 + c
    const int c   = bc & 31;
    const int X0  = xh2 * 64, Y0 = ys * 16;
    const int tid = threadIdx.x;

    const int lane = tid & 63;
    const int wv   = tid >> 6;         // wave: rows [wv*4, wv*4+4)
    const int hi   = lane >> 5;        // k-half
    const int m    = lane & 31;        // A-row x-pixel / D-col n
    const int y_base = wv * 4;

    const float* xbase = x + (size_t)bc * 131072;

    // stage chunk e -> (r = e/68, col = e%68); 1360 chunks total
    auto loadch = [&](int e, float (&v)[8]) {
        int r = e / 68, col = e - r * 68;
        int gy = Y0 - 2 + r, gx = X0 - 2 + col;
        if (gy >= 0 && gy < 128 && gx >= 0 && gx < 128) {
            const float* src = xbase + gy * 128 + gx;
#pragma unroll
            for (int o = 0; o < 8; ++o) v[o] = src[o * 16384];
        } else {
#pragma unroll
            for (int o = 0; o < 8; ++o) v[o] = 0.0f;
        }
    };
    auto packch = [&](int e, const float (&v)[8]) {
        *reinterpret_cast<uint4*>(&stage[e * 8]) =
            make_uint4(pk2(v[0], v[1]), pk2(v[2], v[3]),
                       pk2(v[4], v[5]), pk2(v[6], v[7]));
    };

    // ---- issue ALL staging loads up front (one exposed HBM latency) ----
    float v0[8], v1[8], v2[8], v3[8], v4[8], v5[8];
    loadch(tid, v0);
    loadch(tid + 256, v1);
    loadch(tid + 512, v2);
    loadch(tid + 768, v3);
    loadch(tid + 1024, v4);
    if (tid < 80) loadch(tid + 1280, v5);

    bf16x8 wfrag[20];

    if constexpr (!TAB) {
        // fallback: build [32 n][40 tr][8 o] table (10240 shorts) in the
        // stage region BEFORE packing; barrier-isolated build -> read.
        for (int e = tid; e < 10240; e += 256) {
            int o = e & 7, tr = (e >> 3) % 40, n2 = e / 320;
            int t = n2 & 7, dlt = n2 >> 3;
            int dyr = tr / 5, dx = tr - 5 * dyr;
            int dy  = dyr - dlt;
            float w = (dy >= 0 && dy < 5) ? rot_w(kern, c, t, o, dy, dx) : 0.0f;
            stage[e] = f2bf(w);
        }
        __syncthreads();
#pragma unroll
        for (int s = 0; s < 20; ++s)
            wfrag[s] = *reinterpret_cast<const bf16x8*>(
                &stage[((m * 40) + 2 * s + hi) * 8]);
        __syncthreads();   // wfrag reads done before packch overwrites
    }

    packch(tid, v0);
    packch(tid + 256, v1);
    packch(tid + 512, v2);
    packch(tid + 768, v3);
    packch(tid + 1024, v4);
    if (tid < 80) packch(tid + 1280, v5);

    if constexpr (TAB) {
        // L2-hot weight frags; issued after packs, latency hides under barrier
        const unsigned short* wb = &wtab[((c * 32 + m) * 40 + hi) * 8];
#pragma unroll
        for (int s = 0; s < 20; ++s)
            wfrag[s] = *reinterpret_cast<const bf16x8*>(&wb[s * 16]);
    }
    __syncthreads();

    // ---- compute: 2 super-iters (x0 = 0, 32); 20 MFMA each ----
    f32x16 acc0 = {0}, acc1 = {0};
    {
        const int baseA0 = (y_base * 68 + 0  + m) * 8;
        const int baseA1 = (y_base * 68 + 32 + m) * 8;
#pragma unroll
        for (int s = 0; s < 20; ++s) {
            const int tr0 = 2 * s, tr1 = 2 * s + 1;
            const int t0 = ((tr0 / 5) * 68 + tr0 % 5) * 8;
            const int t1 = ((tr1 / 5) * 68 + tr1 % 5) * 8;
            const int toff = hi ? t1 : t0;
            bf16x8 a0 = *reinterpret_cast<const bf16x8*>(&stage[baseA0 + toff]);
            bf16x8 a1 = *reinterpret_cast<const bf16x8*>(&stage[baseA1 + toff]);
            acc0 = __builtin_amdgcn_mfma_f32_32x32x16_bf16(a0, wfrag[s], acc0, 0, 0, 0);
            acc1 = __builtin_amdgcn_mfma_f32_32x32x16_bf16(a1, wfrag[s], acc1, 0, 0, 0);
        }
    }
    __syncthreads();   // all waves done reading stage; epil overwrites union

    // ---- wave-private epilogue: D col n=(t,Dlt) -> rows y_base+Dlt ----
    const int t_o = m & 7, dlt = m >> 3;
    const int rowb = t_o * EPIL_TS + (y_base + dlt) * EPIL_RP;
#pragma unroll
    for (int q = 0; q < 4; ++q) {
        int xx = q * 8 + 4 * hi;
        *reinterpret_cast<f32x4*>(&epil[rowb + xx]) =
            (f32x4){acc0[4 * q], acc0[4 * q + 1], acc0[4 * q + 2], acc0[4 * q + 3]};
        *reinterpret_cast<f32x4*>(&epil[rowb + 32 + xx]) =
            (f32x4){acc1[4 * q], acc1[4 * q + 1], acc1[4 * q + 2], acc1[4 * q + 3]};
    }
    // no barrier: stores below read only this wave's rows (lgkmcnt orders)

    float* outb = out + (size_t)bc * 131072;
#pragma unroll
    for (int j = 0; j < 8; ++j) {
        int idx = j * 64 + lane;
        int xq  = idx & 15;            // 16 f32x4 per 64-col row
        int y4  = (idx >> 4) & 3;      // row within wave's 4
        int t   = idx >> 6;            // 0..7
        int y   = wv * 4 + y4;
        f32x4 v = *reinterpret_cast<const f32x4*>(
            &epil[t * EPIL_TS + y * EPIL_RP + xq * 4]);
        __builtin_nontemporal_store(v, reinterpret_cast<f32x4*>(
            outb + (size_t)t * 16384 + (size_t)(Y0 + y) * 128 + X0 + xq * 4));
    }
}

extern "C" void kernel_launch(void* const* d_in, const int* in_sizes, int n_in,
                              void* d_out, int out_size, void* d_ws, size_t ws_size,
                              hipStream_t stream) {
    const float* x    = (const float*)d_in[0];
    const float* kern = (const float*)d_in[1];
    float* out = (float*)d_out;
    dim3 block(256);
    if (ws_size >= 327680 * sizeof(unsigned short)) {
        unsigned short* wtab = (unsigned short*)d_ws;
        build_w3<<<dim3(1280), block, 0, stream>>>(kern, wtab);
        se2_mfma<true><<<dim3(4096), block, 0, stream>>>(x, kern, wtab, out);
    } else {
        se2_mfma<false><<<dim3(4096), block, 0, stream>>>(x, kern, nullptr, out);
    }
}

// Round 19
// 51.812 us; speedup vs baseline: 1.2646x; 1.2646x over previous
//
#include <hip/hip_runtime.h>

// SE(2) depthwise group conv via bf16 MFMA 16x16x32 (fp32 accum), Delta-packed,
// SEPARATE (non-union) wave-private epilogue -> zero post-compute barriers,
// per-row-pair epilogue+NT-stores overlapped with remaining compute.
//
// out[b,c,t,y,x] = sum_{o,dy,dx} W[c,t,o,dy,dx] * x[b,c,o,y+dy-2,x+dx-2]
// GEMM per (b,c): D[m=16 pix][n=(t,Dlt)], Dlt in {0,1} packs TWO output rows
// per MFMA. K = 32 row-taps tr=(dyr 0..5, dx 0..4) x 8 o = 256:
// B[(dyr,dx,o)][(t,Dlt)] = w[t][dyr-Dlt, dx] (0 OOR; tr>=30 pad).
// mfma_f32_16x16x32_bf16: A lane: row=l&15 (pixel x-offset), tap tr=cc*4+g.
//   D lane l: col=l&15=(t+8*Dlt), row=(l>>4)*4+reg = pixel -> f32x4.
// Block = 16 rows x 64 cols of one (b,c); 4 waves; wave wv rows wv*4..+3.
// Per pr in {0,1}: 4 xh-chains x 8 MFMA -> epil write -> ds_read -> NT store.
// LDS: stage [20][68][8] bf16 = 21760 B; epil f32 [4 wv][8 t][2 r][68]
// = 17408 B; total 39168 B (4 blocks/CU). Grid 4096, XCD-chunked swizzle.
// Weights: wtab2[c][n16][tr32][o8] bf16 (256 KB) in d_ws (L2-resident).

typedef short bf16x8 __attribute__((ext_vector_type(8)));
typedef float f32x4 __attribute__((ext_vector_type(4)));

#define EPW 1088       // floats per wave in epil: 8t * 2rows * 68
#define EPIL_RP 68     // row pitch in floats

__device__ inline unsigned short f2bf(float f) {   // RNE f32->bf16
    unsigned int u = __float_as_uint(f);
    u += 0x7fffu + ((u >> 16) & 1u);
    return (unsigned short)(u >> 16);
}
__device__ inline unsigned pk2(float a, float b) {
    return (unsigned)f2bf(a) | ((unsigned)f2bf(b) << 16);
}

// cos/sin of 2*pi*t/8, f32. NN-rounding margins >=0.035 -> table-vs-libm safe.
__device__ __constant__ float CA8[8] = {1.0f, 0.70710678f, 0.0f, -0.70710678f,
                                        -1.0f, -0.70710678f, 0.0f, 0.70710678f};
__device__ __constant__ float SA8[8] = {0.0f, 0.70710678f, 1.0f, 0.70710678f,
                                        0.0f, -0.70710678f, -1.0f, -0.70710678f};

__device__ inline float rot_w(const float* __restrict__ kern, int c, int t,
                              int o, int dy, int dx) {
    float ca = CA8[t], sa = SA8[t];
    float xx = (float)dx - 2.0f, yy = (float)dy - 2.0f;
    int iy = (int)rintf(sa * xx + ca * yy + 2.0f);  // RNE == jnp.round
    int ix = (int)rintf(ca * xx - sa * yy + 2.0f);
    if (iy >= 0 && iy < 5 && ix >= 0 && ix < 5) {
        int tp = (o - t) & 7;
        return kern[(c * 8 + tp) * 25 + iy * 5 + ix];
    }
    return 0.0f;
}

// wtab2[((c*16 + n16)*32 + tr)*8 + o], n16 = t + 8*Dlt; 131072 bf16 = 256 KB
__global__ __launch_bounds__(256)
void build_w2(const float* __restrict__ kern, unsigned short* __restrict__ wtab) {
    int e = blockIdx.x * 256 + threadIdx.x;
    if (e >= 131072) return;
    int o   = e & 7;
    int tr  = (e >> 3) & 31;
    int n16 = (e >> 8) & 15;
    int c   = e >> 12;
    int t   = n16 & 7, dlt = n16 >> 3;
    float w = 0.0f;
    if (tr < 30) {
        int dyr = tr / 5, dx = tr - 5 * dyr;
        int dy  = dyr - dlt;
        if (dy >= 0 && dy < 5) w = rot_w(kern, c, t, o, dy, dx);
    }
    wtab[e] = f2bf(w);
}

template <bool TAB>
__global__ __launch_bounds__(256)
void se2_mfma(const float* __restrict__ x, const float* __restrict__ kern,
              const unsigned short* __restrict__ wtab, float* __restrict__ out) {
    __shared__ __align__(16) unsigned short stage[20 * 68 * 8];  // 21760 B
    __shared__ __align__(16) float epil[4 * EPW];                // 17408 B

    // XCD-chunked bijective swizzle: 4096 blocks, 8 XCDs, 512 per XCD.
    const int bid = (blockIdx.x & 7) * 512 + (blockIdx.x >> 3);
    const int xh2 = bid & 1;           // x half: cols 0-63 / 64-127
    const int ys  = (bid >> 1) & 7;    // 8 row-strips of 16
    const int bc  = bid >> 4;          // b*32 + c
    const int c   = bc & 31;
    const int X0  = xh2 * 64, Y0 = ys * 16;
    const int tid = threadIdx.x;

    const int lane = tid & 63;
    const int wv   = tid >> 6;         // wave: rows [wv*4, wv*4+4)
    const int g    = lane >> 4;        // k-group (4 row-taps)
    const int m16  = lane & 15;        // A-row pixel / D-col n16

    const float* xbase = x + (size_t)bc * 131072;

    // stage chunk e -> (r = e/68, col = e%68); 1360 chunks total
    auto loadch = [&](int e, float (&v)[8]) {
        int r = e / 68, col = e - r * 68;
        int gy = Y0 - 2 + r, gx = X0 - 2 + col;
        if (gy >= 0 && gy < 128 && gx >= 0 && gx < 128) {
            const float* src = xbase + gy * 128 + gx;
#pragma unroll
            for (int o = 0; o < 8; ++o) v[o] = src[o * 16384];
        } else {
#pragma unroll
            for (int o = 0; o < 8; ++o) v[o] = 0.0f;
        }
    };
    auto packch = [&](int e, const float (&v)[8]) {
        *reinterpret_cast<uint4*>(&stage[e * 8]) =
            make_uint4(pk2(v[0], v[1]), pk2(v[2], v[3]),
                       pk2(v[4], v[5]), pk2(v[6], v[7]));
    };

    // ---- issue ALL staging loads up front (one exposed HBM latency) ----
    float v0[8], v1[8], v2[8], v3[8], v4[8], v5[8];
    loadch(tid, v0);
    loadch(tid + 256, v1);
    loadch(tid + 512, v2);
    loadch(tid + 768, v3);
    loadch(tid + 1024, v4);
    if (tid < 80) loadch(tid + 1280, v5);

    bf16x8 wfrag[8];
    int    tapoff[8];
#pragma unroll
    for (int cc = 0; cc < 8; ++cc) {
        int tr  = cc * 4 + g;
        int trc = tr < 30 ? tr : 29;   // A addr clamp (B weight is zero there)
        int dyr = trc / 5, dx = trc - 5 * dyr;
        tapoff[cc] = (dyr * 68 + dx) * 8;          // in shorts
        if constexpr (TAB)
            wfrag[cc] = *reinterpret_cast<const bf16x8*>(
                &wtab[((c * 16 + m16) * 32 + tr) * 8]);
    }

    if constexpr (!TAB) {
        // fallback: build [16 n][32 tr][8 o] table in stage before packing
        for (int e = tid; e < 4096; e += 256) {
            int o = e & 7, tr = (e >> 3) & 31, n16 = e >> 8;
            int t = n16 & 7, dlt = n16 >> 3;
            float w = 0.0f;
            if (tr < 30) {
                int dyr = tr / 5, dx = tr - 5 * dyr;
                int dy  = dyr - dlt;
                if (dy >= 0 && dy < 5) w = rot_w(kern, c, t, o, dy, dx);
            }
            stage[e] = f2bf(w);
        }
        __syncthreads();
#pragma unroll
        for (int cc = 0; cc < 8; ++cc)
            wfrag[cc] = *reinterpret_cast<const bf16x8*>(
                &stage[(m16 * 32 + cc * 4 + g) * 8]);
        __syncthreads();   // wfrag reads done before packch overwrites region
    }

    packch(tid, v0);
    packch(tid + 256, v1);
    packch(tid + 512, v2);
    packch(tid + 768, v3);
    packch(tid + 1024, v4);
    if (tid < 80) packch(tid + 1280, v5);
    __syncthreads();       // the ONLY block-wide barrier on the TAB path

    const int t_o = m16 & 7, dlt = m16 >> 3;
    float* outb = out + (size_t)bc * 131072;
    float* ep   = &epil[wv * EPW];

    // ---- 2 row-pairs; per pr: compute (4 xh chains) -> epil -> NT store ----
#pragma unroll
    for (int pr = 0; pr < 2; ++pr) {
        const int yl = wv * 4 + pr * 2;
        f32x4 acc0 = {0.f, 0.f, 0.f, 0.f};
        f32x4 acc1 = {0.f, 0.f, 0.f, 0.f};
        f32x4 acc2 = {0.f, 0.f, 0.f, 0.f};
        f32x4 acc3 = {0.f, 0.f, 0.f, 0.f};
        const int baseS = (yl * 68 + m16) * 8;
#pragma unroll
        for (int cc = 0; cc < 8; ++cc) {
            const unsigned short* ps = &stage[baseS + tapoff[cc]];
            bf16x8 x0 = *reinterpret_cast<const bf16x8*>(ps);
            bf16x8 x1 = *reinterpret_cast<const bf16x8*>(ps + 128);
            bf16x8 x2 = *reinterpret_cast<const bf16x8*>(ps + 256);
            bf16x8 x3 = *reinterpret_cast<const bf16x8*>(ps + 384);
            acc0 = __builtin_amdgcn_mfma_f32_16x16x32_bf16(x0, wfrag[cc], acc0, 0, 0, 0);
            acc1 = __builtin_amdgcn_mfma_f32_16x16x32_bf16(x1, wfrag[cc], acc1, 0, 0, 0);
            acc2 = __builtin_amdgcn_mfma_f32_16x16x32_bf16(x2, wfrag[cc], acc2, 0, 0, 0);
            acc3 = __builtin_amdgcn_mfma_f32_16x16x32_bf16(x3, wfrag[cc], acc3, 0, 0, 0);
        }

        // epil write: lane owns (t_o, dlt) row of this pr; 4 xh quads
        float* ew = ep + (t_o * 2 + dlt) * EPIL_RP;
        *reinterpret_cast<f32x4*>(ew + 0  + g * 4) = acc0;
        *reinterpret_cast<f32x4*>(ew + 16 + g * 4) = acc1;
        *reinterpret_cast<f32x4*>(ew + 32 + g * 4) = acc2;
        *reinterpret_cast<f32x4*>(ew + 48 + g * 4) = acc3;
        // same-wave LDS order (lgkmcnt) makes these visible to the reads below

#pragma unroll
        for (int j = 0; j < 4; ++j) {
            int idx = j * 64 + lane;
            int xq  = idx & 15;            // 16 f32x4 per 64-col row
            int y2  = (idx >> 4) & 1;      // row within pair
            int tt  = idx >> 5;            // 0..7
            f32x4 v = *reinterpret_cast<const f32x4*>(
                ep + (tt * 2 + y2) * EPIL_RP + xq * 4);
            __builtin_nontemporal_store(v, reinterpret_cast<f32x4*>(
                outb + (size_t)tt * 16384 +
                (size_t)(Y0 + yl + y2) * 128 + X0 + xq * 4));
        }
    }
}

extern "C" void kernel_launch(void* const* d_in, const int* in_sizes, int n_in,
                              void* d_out, int out_size, void* d_ws, size_t ws_size,
                              hipStream_t stream) {
    const float* x    = (const float*)d_in[0];
    const float* kern = (const float*)d_in[1];
    float* out = (float*)d_out;
    dim3 block(256);
    if (ws_size >= 131072 * sizeof(unsigned short)) {
        unsigned short* wtab = (unsigned short*)d_ws;
        build_w2<<<dim3(512), block, 0, stream>>>(kern, wtab);
        se2_mfma<true><<<dim3(4096), block, 0, stream>>>(x, kern, wtab, out);
    } else {
        se2_mfma<false><<<dim3(4096), block, 0, stream>>>(x, kern, nullptr, out);
    }
}